// Round 21
// baseline (916.741 us; speedup 1.0000x reference)
//
#include <hip/hip_runtime.h>
#include <hip/hip_fp16.h>
#include <stdint.h>

typedef int i32x4 __attribute__((ext_vector_type(4)));

#define IN_F  4096
#define OUT_F 11008
#define MROWS 8192
#define BM 256
#define BN 256
#define BKB 64                     // K-bytes per tile (i8) -> one 16x16x64 K-depth
#define NKT (IN_F / BKB)           // 64
#define GRID_M (MROWS / BM)        // 32
#define GRID_N (OUT_F / BN)        // 43
#define NBLK (GRID_M * GRID_N)     // 1376 (divisible by 8 -> bijective XCD swizzle)
#define QBLKS 16384                // quant blocks: (8192*4096/8)/256
#define PBLKS 22016                // pack blocks:  (11008*4096/8)/256

#define AS1 __attribute__((address_space(1)))
#define AS3 __attribute__((address_space(3)))

// ---------------- Fused pre-pass: quant activations ⊕ pack weights ----------------
__global__ __launch_bounds__(256) void prep_kernel(
    const float* __restrict__ x, const float* __restrict__ pqs,
    const float* __restrict__ iscale, int8_t* __restrict__ q,
    const int* __restrict__ w, int8_t* __restrict__ wq)
{
    const int blk = blockIdx.x;
    if (blk < QBLKS) {
        const int i = blk * 256 + threadIdx.x;
        const float s = iscale[0];
        const size_t base = (size_t)i * 8;
        const int col = (int)(base & (IN_F - 1));

        const float4 x0 = *(const float4*)(x + base);
        const float4 x1 = *(const float4*)(x + base + 4);
        const float4 p0 = *(const float4*)(pqs + col);
        const float4 p1 = *(const float4*)(pqs + col + 4);

        float xs[8];
        xs[0] = x0.x * p0.x; xs[1] = x0.y * p0.y; xs[2] = x0.z * p0.z; xs[3] = x0.w * p0.w;
        xs[4] = x1.x * p1.x; xs[5] = x1.y * p1.y; xs[6] = x1.z * p1.z; xs[7] = x1.w * p1.w;

        unsigned int lo = 0, hi = 0;
        #pragma unroll
        for (int j = 0; j < 8; ++j) {
            float xm = __half2float(__float2half(xs[j]));   // fp16 Mul materialization
            float qf = nearbyintf(xm / s);                  // f32 div + RNE (np.round)
            qf = fminf(fmaxf(qf, -128.0f), 127.0f);
            unsigned int b = (unsigned int)((int)qf & 0xff);
            if (j < 4) lo |= b << (8 * j);
            else       hi |= b << (8 * (j - 4));
        }
        *(uint2*)(q + base) = make_uint2(lo, hi);
    } else {
        const size_t i = ((size_t)(blk - QBLKS) * 256 + threadIdx.x) * 8;
        const int4 a = *(const int4*)(w + i);
        const int4 b = *(const int4*)(w + i + 4);
        unsigned int lo = (a.x & 0xff) | ((a.y & 0xff) << 8) | ((a.z & 0xff) << 16) | ((unsigned int)(a.w & 0xff) << 24);
        unsigned int hi = (b.x & 0xff) | ((b.y & 0xff) << 8) | ((b.z & 0xff) << 16) | ((unsigned int)(b.w & 0xff) << 24);
        *(uint2*)(wq + i) = make_uint2(lo, hi);
    }
}

// ---------------- 256x256 i8 GEMM: A via LDS (quad-buffer), B DIRECT from global ----------------
// r18 counters showed LDS-port-bound (~1800 of 2434 cyc/CU/K-tile; MFMA needs 310).
// Fix: remove B from LDS entirely. B frags = per-wave global_load_dwordx4 from L1/L2
// (each 64-B line fully consumed by the 4 hk-lanes; wr-duplicate waves L1-hit).
// LDS now A only: 4 bufs x 16 KB = 64 KB; reads 64/tile/CU (~770 cyc) + writes
// (~128) -> LDS off the critical path; B rides the independent TCP/L2 pipe.
// Skeleton = r18 (race-clean): read-ahead a(kt+1) during cluster kt; stage A(kt+3)
// -> buf (kt-1)&3 (1-iter WAR slack). A-ledger (1 A-stage + 4 B-loads/thread/tile):
// top of iter kt needs A(kt+1) resident; outstanding newer = A(kt+2) + B(kt)x4 = 5
// -> vmcnt(5); tail vmcnt(4). B-reg deps are compiler-tracked (it inserts waits).
// Swizzle (A only, 0-conflict proven r11): chunk ^= (row>>1)&3, both sides.
__global__ __launch_bounds__(1024, 4) void gemm_i8_256_kernel(
    const int8_t* __restrict__ Aq,     // [8192][4096]
    const int8_t* __restrict__ Wq,     // [11008][4096]
    const float* __restrict__ wscale,  // [11008]
    const float* __restrict__ iscale,  // [1]
    float* __restrict__ out)           // [8192][11008] f32
{
    __shared__ int8_t lds[65536];      // 4 x 16384, A tiles only

    const int tid  = threadIdx.x;
    const int lane = tid & 63;
    const int wv   = tid >> 6;         // 0..15
    const int wr   = wv >> 2;          // 0..3  (M quarter)
    const int wc   = wv & 3;           // 0..3  (N quarter)

    // T1: XCD-aware swizzle
    const int bid = (int)blockIdx.x;
    const int swz = (bid & 7) * (NBLK / 8) + (bid >> 3);
    const int bm = swz / GRID_N;
    const int bn = swz % GRID_N;
    const int brow = bm * BM, bcol = bn * BN;

    const int8_t* Ab = Aq + (size_t)brow * IN_F;

    // A staging: 1024 16B-chunks per tile; ONE chunk per thread
    const int srow = tid >> 2;                              // tile row (0..255)
    const int scol = ((tid & 3) ^ ((srow >> 1) & 3)) * 16;  // inverse-swizzled source
    const int sdst = tid * 16;                              // linear LDS dest

    #define STAGE_A(t) __builtin_amdgcn_global_load_lds( \
        (const AS1 void*)(Ab + (size_t)srow * IN_F + (t) * BKB + scol), \
        (AS3 void*)(lds + ((t) & 3) * 16384 + sdst), 16, 0, 0)

    i32x4 acc[4][4] = {};
    i32x4 a[4], b[4];

    const int rl = lane & 15;
    const int hk = lane >> 4;                          // K-quarter 0..3
    const int koff = (hk ^ ((rl >> 1) & 3)) * 16;      // bank-exact swizzled chunk
    const int a_base = (wr * 64 + rl) * 64;            // + mf*1024 + koff

    // B direct-global per-lane base: row = bcol + wc*64 + nf*16 + rl, byte k = kt*64 + hk*16
    const int8_t* Bg = Wq + (size_t)(bcol + wc * 64 + rl) * IN_F + hk * 16;

    // prologue: stage A tiles 0,1,2; wait tile 0; read a(0) frags; load b(0)
    STAGE_A(0);
    STAGE_A(1);
    STAGE_A(2);
    asm volatile("s_waitcnt vmcnt(2)" ::: "memory");   // A(0) staged
    __builtin_amdgcn_s_barrier();
    #pragma unroll
    for (int mf = 0; mf < 4; ++mf)
        a[mf] = *(const i32x4*)(lds + a_base + mf * 1024 + koff);
    #pragma unroll
    for (int nf = 0; nf < 4; ++nf)
        b[nf] = *(const i32x4*)(Bg + (size_t)nf * 16 * IN_F);

    for (int kt = 0; kt < NKT; ++kt) {
        // A(kt+1) resident: outstanding newer = A(kt+2) [if staged] + B(kt)x4
        if (kt + 3 < NKT + 1) { /* kt+2 <= NKT-1 staged path */ }
        if (kt + 2 < NKT) asm volatile("s_waitcnt vmcnt(5)" ::: "memory");
        else              asm volatile("s_waitcnt vmcnt(4)" ::: "memory");
        asm volatile("s_waitcnt lgkmcnt(0)" ::: "memory");  // own a(kt) frag reads done
        __builtin_amdgcn_s_barrier();          // all waves' a(kt) reads done

        if (kt + 3 < NKT) STAGE_A(kt + 3);     // buf (kt-1)&3: 1-iter WAR slack

        __builtin_amdgcn_sched_barrier(0);     // rule #18: pin MFMAs below the waits

        const int8_t* An = lds + ((kt + 1) & 3) * 16384;    // next A-tile base
        const bool more = (kt + 1 < NKT);

        #pragma unroll
        for (int mf = 0; mf < 4; ++mf) {
            #pragma unroll
            for (int nf = 0; nf < 4; ++nf)
                acc[mf][nf] = __builtin_amdgcn_mfma_i32_16x16x64_i8(a[mf], b[nf], acc[mf][nf], 0, 0, 0);
            if (more)  // a[mf] dead after its row: rotate in next tile's frag (LDS)
                a[mf] = *(const i32x4*)(An + a_base + mf * 1024 + koff);
        }
        if (more) {
            const int8_t* Bk = Bg + (kt + 1) * BKB;
            #pragma unroll
            for (int nf = 0; nf < 4; ++nf)     // b dead after cluster: rotate (global/L1)
                b[nf] = *(const i32x4*)(Bk + (size_t)nf * 16 * IN_F);
        }
        __builtin_amdgcn_sched_barrier(0);
    }

    // epilogue: out = f32(acc * s * ws[col]); C/D map: col=lane&15, row=hk*4+j
    const float s = iscale[0];
    #pragma unroll
    for (int nf = 0; nf < 4; ++nf) {
        const int col = bcol + wc * 64 + nf * 16 + rl;
        const float sc = s * wscale[col];
        #pragma unroll
        for (int mf = 0; mf < 4; ++mf) {
            const int r0 = brow + wr * 64 + mf * 16 + hk * 4;
            #pragma unroll
            for (int j = 0; j < 4; ++j)
                out[(size_t)(r0 + j) * OUT_F + col] = (float)acc[mf][nf][j] * sc;
        }
    }
    #undef STAGE_A
}

// ---------------- Scalar fallback (no workspace), pathological ws only ----------------
__global__ __launch_bounds__(256) void simple_ref_kernel(
    const float* __restrict__ x, const int* __restrict__ w,
    const float* __restrict__ wsc, const float* __restrict__ isc,
    const float* __restrict__ pqs, float* __restrict__ out)
{
    const float s = isc[0];
    const int m = blockIdx.x;
    const int o = blockIdx.y * 256 + threadIdx.x;
    if (o >= OUT_F) return;
    const float wso = wsc[o];
    const float* xr = x + (size_t)m * IN_F;
    const int* wr = w + (size_t)o * IN_F;
    float acc = 0.0f;
    for (int k = 0; k < IN_F; ++k) {
        float xm = __half2float(__float2half(xr[k] * pqs[k]));
        float qf = nearbyintf(xm / s);
        qf = fminf(fmaxf(qf, -128.0f), 127.0f);
        float xdq = __half2float(__float2half(qf * s));
        float wdq = __half2float(__float2half((float)wr[k] * wso));
        acc = fmaf(xdq, wdq, acc);
    }
    out[(size_t)m * OUT_F + o] = acc;
}

extern "C" void kernel_launch(void* const* d_in, const int* in_sizes, int n_in,
                              void* d_out, int out_size, void* d_ws, size_t ws_size,
                              hipStream_t stream)
{
    const float* x   = nullptr;
    const int*   w   = nullptr;
    const float* wsc = nullptr;
    const float* isc = nullptr;
    const float* pqs = nullptr;
    for (int i = 0; i < n_in; ++i) {
        switch (in_sizes[i]) {
            case MROWS * IN_F:   x   = (const float*)d_in[i]; break; // 33554432
            case OUT_F * IN_F:   w   = (const int*)d_in[i];   break; // 45088768
            case OUT_F:          wsc = (const float*)d_in[i]; break; // 11008
            case 1:              isc = (const float*)d_in[i]; break;
            case IN_F:           pqs = (const float*)d_in[i]; break; // 4096
        }
    }
    float* out = (float*)d_out;   // fp16 reference output -> float32 buffer

    const size_t need = (size_t)MROWS * IN_F + (size_t)OUT_F * IN_F;  // 78.6 MB
    if (d_ws == nullptr || ws_size < need) {
        dim3 grid(MROWS, (OUT_F + 255) / 256);
        simple_ref_kernel<<<grid, 256, 0, stream>>>(x, w, wsc, isc, pqs, out);
        return;
    }

    int8_t* Aq = (int8_t*)d_ws;
    int8_t* Wq = Aq + (size_t)MROWS * IN_F;

    prep_kernel<<<QBLKS + PBLKS, 256, 0, stream>>>(x, pqs, isc, Aq, w, Wq);
    gemm_i8_256_kernel<<<NBLK, 1024, 0, stream>>>(Aq, Wq, wsc, isc, out);
}

// Round 22
// 470.162 us; speedup vs baseline: 1.9498x; 1.9498x over previous
//
#include <hip/hip_runtime.h>
#include <hip/hip_fp16.h>
#include <stdint.h>

typedef int i32x4 __attribute__((ext_vector_type(4)));

#define IN_F  4096
#define OUT_F 11008
#define MROWS 8192
#define BM 256
#define BN 256
#define BKB 64                     // K-bytes per tile (i8) -> one 16x16x64 K-depth
#define NKT (IN_F / BKB)           // 64
#define GRID_M (MROWS / BM)        // 32
#define GRID_N (OUT_F / BN)        // 43
#define NBLK (GRID_M * GRID_N)     // 1376 (divisible by 8 -> bijective XCD swizzle)
#define QBLKS 16384                // quant blocks: (8192*4096/8)/256
#define PBLKS 22016                // pack blocks:  (11008*4096/8)/256

#define AS1 __attribute__((address_space(1)))
#define AS3 __attribute__((address_space(3)))

// ---------------- Fused pre-pass: quant activations ⊕ pack weights (independent jobs) ----------------
__global__ __launch_bounds__(256) void prep_kernel(
    const float* __restrict__ x, const float* __restrict__ pqs,
    const float* __restrict__ iscale, int8_t* __restrict__ q,
    const int* __restrict__ w, int8_t* __restrict__ wq)
{
    const int blk = blockIdx.x;
    if (blk < QBLKS) {
        // quant: one thread per 8 elements of x
        const int i = blk * 256 + threadIdx.x;
        const float s = iscale[0];
        const size_t base = (size_t)i * 8;
        const int col = (int)(base & (IN_F - 1));

        const float4 x0 = *(const float4*)(x + base);
        const float4 x1 = *(const float4*)(x + base + 4);
        const float4 p0 = *(const float4*)(pqs + col);
        const float4 p1 = *(const float4*)(pqs + col + 4);

        float xs[8];
        xs[0] = x0.x * p0.x; xs[1] = x0.y * p0.y; xs[2] = x0.z * p0.z; xs[3] = x0.w * p0.w;
        xs[4] = x1.x * p1.x; xs[5] = x1.y * p1.y; xs[6] = x1.z * p1.z; xs[7] = x1.w * p1.w;

        unsigned int lo = 0, hi = 0;
        #pragma unroll
        for (int j = 0; j < 8; ++j) {
            float xm = __half2float(__float2half(xs[j]));   // fp16 Mul materialization
            float qf = nearbyintf(xm / s);                  // f32 div + RNE (np.round)
            qf = fminf(fmaxf(qf, -128.0f), 127.0f);
            unsigned int b = (unsigned int)((int)qf & 0xff);
            if (j < 4) lo |= b << (8 * j);
            else       hi |= b << (8 * (j - 4));
        }
        *(uint2*)(q + base) = make_uint2(lo, hi);
    } else {
        // pack: one thread per 8 int32 weights
        const size_t i = ((size_t)(blk - QBLKS) * 256 + threadIdx.x) * 8;
        const int4 a = *(const int4*)(w + i);
        const int4 b = *(const int4*)(w + i + 4);
        unsigned int lo = (a.x & 0xff) | ((a.y & 0xff) << 8) | ((a.z & 0xff) << 16) | ((unsigned int)(a.w & 0xff) << 24);
        unsigned int hi = (b.x & 0xff) | ((b.y & 0xff) << 8) | ((b.z & 0xff) << 16) | ((unsigned int)(b.w & 0xff) << 24);
        *(uint2*)(wq + i) = make_uint2(lo, hi);
    }
}

// ---------------- 256x256 i8 GEMM (r14/r18 config: best measured, race-clean) ----------------
// 16 waves (4x4 of 64x64), 4 waves/SIMD; quad buffer 4x32KB; read-ahead frag
// pipeline (tile kt+1's frags ds_read during kt's MFMA cluster, rotating into
// dead frag regs); counted vmcnt (2 loads/thread/tile): iter kt waits vmcnt(2)
// -> tile kt+1 resident; stage(kt+3) -> buf (kt-1)&3 (one full iter of WAR
// slack -- r16's zero-slack triple buffer raced). Swizzle chunk ^= (row>>1)&3
// both sides: 0 bank conflicts measured.
__global__ __launch_bounds__(1024, 4) void gemm_i8_256_kernel(
    const int8_t* __restrict__ Aq,     // [8192][4096]
    const int8_t* __restrict__ Wq,     // [11008][4096]
    const float* __restrict__ wscale,  // [11008]
    const float* __restrict__ iscale,  // [1]
    float* __restrict__ out)           // [8192][11008] f32
{
    __shared__ int8_t lds[131072];     // 4 x 32768 (A 16K | B 16K)

    const int tid  = threadIdx.x;
    const int lane = tid & 63;
    const int wv   = tid >> 6;         // 0..15
    const int wr   = wv >> 2;          // 0..3  (M quarter)
    const int wc   = wv & 3;           // 0..3  (N quarter)

    // T1: XCD-aware swizzle
    const int bid = (int)blockIdx.x;
    const int swz = (bid & 7) * (NBLK / 8) + (bid >> 3);
    const int bm = swz / GRID_N;
    const int bn = swz % GRID_N;
    const int brow = bm * BM, bcol = bn * BN;

    const int8_t* Ab = Aq + (size_t)brow * IN_F;
    const int8_t* Bb = Wq + (size_t)bcol * IN_F;

    // staging: 1024 16B-chunks per operand tile; ONE chunk per thread per operand
    const int srow = tid >> 2;                              // tile row (0..255)
    const int scol = ((tid & 3) ^ ((srow >> 1) & 3)) * 16;  // inverse-swizzled source
    const int sdst = tid * 16;                              // linear LDS dest

    #define STAGE_A(t) __builtin_amdgcn_global_load_lds( \
        (const AS1 void*)(Ab + (size_t)srow * IN_F + (t) * BKB + scol), \
        (AS3 void*)(lds + ((t) & 3) * 32768 + sdst), 16, 0, 0)
    #define STAGE_B(t) __builtin_amdgcn_global_load_lds( \
        (const AS1 void*)(Bb + (size_t)srow * IN_F + (t) * BKB + scol), \
        (AS3 void*)(lds + ((t) & 3) * 32768 + 16384 + sdst), 16, 0, 0)

    i32x4 acc[4][4] = {};
    i32x4 a[4], b[4];

    const int rl = lane & 15;
    const int hk = lane >> 4;                          // K-quarter 0..3
    const int koff = (hk ^ ((rl >> 1) & 3)) * 16;      // bank-exact swizzled chunk
    const int a_base = (wr * 64 + rl) * 64;            // + mf*1024 + koff
    const int b_base = (wc * 64 + rl) * 64;            // + nf*1024 + koff

    // prologue: stage tiles 0,1,2; wait tile 0; read tile-0 frags
    STAGE_A(0); STAGE_B(0);
    STAGE_A(1); STAGE_B(1);
    STAGE_A(2); STAGE_B(2);
    asm volatile("s_waitcnt vmcnt(4)" ::: "memory");   // tile 0 staged
    __builtin_amdgcn_s_barrier();
    #pragma unroll
    for (int mf = 0; mf < 4; ++mf)
        a[mf] = *(const i32x4*)(lds + a_base + mf * 1024 + koff);
    #pragma unroll
    for (int nf = 0; nf < 4; ++nf)
        b[nf] = *(const i32x4*)(lds + 16384 + b_base + nf * 1024 + koff);

    for (int kt = 0; kt < NKT; ++kt) {
        if (kt + 2 < NKT) asm volatile("s_waitcnt vmcnt(2)" ::: "memory");  // tile kt+1 resident
        else              asm volatile("s_waitcnt vmcnt(0)" ::: "memory");
        asm volatile("s_waitcnt lgkmcnt(0)" ::: "memory");  // own tile-kt frag reads done
        __builtin_amdgcn_s_barrier();          // all waves' tile-kt reads done

        if (kt + 3 < NKT) { STAGE_A(kt + 3); STAGE_B(kt + 3); }  // buf (kt-1)&3: 1-iter slack

        __builtin_amdgcn_sched_barrier(0);     // rule #18: pin MFMAs below the waits

        const int8_t* An = lds + ((kt + 1) & 3) * 32768;    // next-tile bases
        const int8_t* Bn = An + 16384;
        const bool more = (kt + 1 < NKT);

        #pragma unroll
        for (int mf = 0; mf < 4; ++mf) {
            #pragma unroll
            for (int nf = 0; nf < 4; ++nf)
                acc[mf][nf] = __builtin_amdgcn_mfma_i32_16x16x64_i8(a[mf], b[nf], acc[mf][nf], 0, 0, 0);
            if (more)  // a[mf] dead after its row: rotate in next tile's frag
                a[mf] = *(const i32x4*)(An + a_base + mf * 1024 + koff);
        }
        if (more) {
            #pragma unroll
            for (int nf = 0; nf < 4; ++nf)     // b dead after cluster
                b[nf] = *(const i32x4*)(Bn + b_base + nf * 1024 + koff);
        }
        __builtin_amdgcn_sched_barrier(0);
    }

    // epilogue: out = f32(acc * s * ws[col]); C/D map: col=lane&15, row=hk*4+j
    const float s = iscale[0];
    #pragma unroll
    for (int nf = 0; nf < 4; ++nf) {
        const int col = bcol + wc * 64 + nf * 16 + rl;
        const float sc = s * wscale[col];
        #pragma unroll
        for (int mf = 0; mf < 4; ++mf) {
            const int r0 = brow + wr * 64 + mf * 16 + hk * 4;
            #pragma unroll
            for (int j = 0; j < 4; ++j)
                out[(size_t)(r0 + j) * OUT_F + col] = (float)acc[mf][nf][j] * sc;
        }
    }
    #undef STAGE_A
    #undef STAGE_B
}

// ---------------- Scalar fallback (no workspace), pathological ws only ----------------
__global__ __launch_bounds__(256) void simple_ref_kernel(
    const float* __restrict__ x, const int* __restrict__ w,
    const float* __restrict__ wsc, const float* __restrict__ isc,
    const float* __restrict__ pqs, float* __restrict__ out)
{
    const float s = isc[0];
    const int m = blockIdx.x;
    const int o = blockIdx.y * 256 + threadIdx.x;
    if (o >= OUT_F) return;
    const float wso = wsc[o];
    const float* xr = x + (size_t)m * IN_F;
    const int* wr = w + (size_t)o * IN_F;
    float acc = 0.0f;
    for (int k = 0; k < IN_F; ++k) {
        float xm = __half2float(__float2half(xr[k] * pqs[k]));
        float qf = nearbyintf(xm / s);
        qf = fminf(fmaxf(qf, -128.0f), 127.0f);
        float xdq = __half2float(__float2half(qf * s));
        float wdq = __half2float(__float2half((float)wr[k] * wso));
        acc = fmaf(xdq, wdq, acc);
    }
    out[(size_t)m * OUT_F + o] = acc;
}

extern "C" void kernel_launch(void* const* d_in, const int* in_sizes, int n_in,
                              void* d_out, int out_size, void* d_ws, size_t ws_size,
                              hipStream_t stream)
{
    const float* x   = nullptr;
    const int*   w   = nullptr;
    const float* wsc = nullptr;
    const float* isc = nullptr;
    const float* pqs = nullptr;
    for (int i = 0; i < n_in; ++i) {
        switch (in_sizes[i]) {
            case MROWS * IN_F:   x   = (const float*)d_in[i]; break; // 33554432
            case OUT_F * IN_F:   w   = (const int*)d_in[i];   break; // 45088768
            case OUT_F:          wsc = (const float*)d_in[i]; break; // 11008
            case 1:              isc = (const float*)d_in[i]; break;
            case IN_F:           pqs = (const float*)d_in[i]; break; // 4096
        }
    }
    float* out = (float*)d_out;   // fp16 reference output -> float32 buffer

    const size_t need = (size_t)MROWS * IN_F + (size_t)OUT_F * IN_F;  // 78.6 MB
    if (d_ws == nullptr || ws_size < need) {
        dim3 grid(MROWS, (OUT_F + 255) / 256);
        simple_ref_kernel<<<grid, 256, 0, stream>>>(x, w, wsc, isc, pqs, out);
        return;
    }

    int8_t* Aq = (int8_t*)d_ws;
    int8_t* Wq = Aq + (size_t)MROWS * IN_F;

    prep_kernel<<<QBLKS + PBLKS, 256, 0, stream>>>(x, pqs, isc, Aq, w, Wq);
    gemm_i8_256_kernel<<<NBLK, 1024, 0, stream>>>(Aq, Wq, wsc, isc, out);
}